// Round 6
// baseline (5560.406 us; speedup 1.0000x reference)
//
#include <hip/hip_runtime.h>

typedef unsigned short u16;
typedef unsigned int u32;
typedef unsigned long long u64;
typedef __attribute__((ext_vector_type(8))) short short8v;
typedef __attribute__((ext_vector_type(4))) short short4v;
typedef __attribute__((ext_vector_type(8))) __bf16 bf16x8;
typedef __attribute__((ext_vector_type(4))) float f32x4;
typedef __attribute__((ext_vector_type(2))) float f32x2;

#define AS1 __attribute__((address_space(1)))
#define AS3 __attribute__((address_space(3)))

// ---------- helpers ----------
__device__ __forceinline__ u16 f2bf(float f) {
  unsigned u = __float_as_uint(f);
  u += 0x7fffu + ((u >> 16) & 1u);   // round-to-nearest-even
  return (u16)(u >> 16);
}
__device__ __forceinline__ float bf2f(u16 h) {
  return __uint_as_float(((unsigned)h) << 16);
}
__device__ __forceinline__ void gload_lds16(const void* g, void* l) {
  __builtin_amdgcn_global_load_lds((const AS1 void*)g, (AS3 void*)l, 16, 0, 0);
}
__device__ __forceinline__ bf16x8 ld8(const u16* p) {
  return __builtin_bit_cast(bf16x8, *reinterpret_cast<const short8v*>(p));
}
__device__ __forceinline__ float sigf(float x) { return 1.0f / (1.0f + __expf(-x)); }
__device__ __forceinline__ float tanhfast(float x) {
  float e = __expf(2.0f * x);
  return 1.0f - 2.0f / (e + 1.0f);
}

// ---------- setup kernels ----------
__global__ __launch_bounds__(256) void k_conv_x(const float* __restrict__ x,
                                                u16* __restrict__ xh) {
  int i = blockIdx.x * 256 + threadIdx.x;
  float4 v = reinterpret_cast<const float4*>(x)[i];
  ushort4 o;
  o.x = f2bf(v.x); o.y = f2bf(v.y); o.z = f2bf(v.z); o.w = f2bf(v.w);
  reinterpret_cast<ushort4*>(xh)[i] = o;
}

// gate-interleaved packing: n' = d*2048 + 4j + g, src row = g*512 + j
__global__ __launch_bounds__(256) void k_pack_w(
    const float* __restrict__ Wx_f, const float* __restrict__ Wh_f,
    const float* __restrict__ bx_f, const float* __restrict__ bh_f,
    const float* __restrict__ Wx_b, const float* __restrict__ Wh_b,
    const float* __restrict__ bx_b, const float* __restrict__ bh_b,
    u16* __restrict__ wall, u16* __restrict__ whp, float* __restrict__ bias) {
  int i = blockIdx.x * 256 + threadIdx.x;
  int np = i >> 7;
  int k4 = i & 127;
  int d  = np >> 11;
  int p  = np & 2047;
  int src = (p & 3) * 512 + (p >> 2);
  const float* wx = d ? Wx_b : Wx_f;
  const float* wh = d ? Wh_b : Wh_f;
  float4 vx = reinterpret_cast<const float4*>(wx + (size_t)src * 512)[k4];
  float4 vh = reinterpret_cast<const float4*>(wh + (size_t)src * 512)[k4];
  ushort4 ox, oh;
  ox.x = f2bf(vx.x); ox.y = f2bf(vx.y); ox.z = f2bf(vx.z); ox.w = f2bf(vx.w);
  oh.x = f2bf(vh.x); oh.y = f2bf(vh.y); oh.z = f2bf(vh.z); oh.w = f2bf(vh.w);
  reinterpret_cast<ushort4*>(wall + (size_t)np * 512)[k4] = ox;
  reinterpret_cast<ushort4*>(whp  + (size_t)np * 512)[k4] = oh;
  if (k4 == 0) bias[np] = d ? (bx_b[src] + bh_b[src]) : (bx_f[src] + bh_f[src]);
}

// ---------- phase 1: xg = xh @ wall^T + bias ----------
template <bool XGBF16>
__global__ __launch_bounds__(256) void k_gemm_xg(
    const u16* __restrict__ A, const u16* __restrict__ Bw,
    const float* __restrict__ bias,
    float* __restrict__ Cf, u16* __restrict__ Ch) {
  __shared__ __align__(16) u16 lA[128 * 32];
  __shared__ __align__(16) u16 lB[128 * 32];
  const int tid  = threadIdx.x;
  const int lane = tid & 63;
  const int w    = tid >> 6;
  const int wr   = w >> 1, wc = w & 1;
  const size_t brow = (size_t)blockIdx.y * 128;
  const int    bcol = blockIdx.x * 128;

  f32x4 acc[4][4] = {};

  for (int kk = 0; kk < 16; ++kk) {
    const int k0 = kk * 32;
    __syncthreads();
#pragma unroll
    for (int q = 0; q < 2; ++q) {
      int idx = q * 256 + tid;
      int row = idx >> 2, c = idx & 3;
      gload_lds16(A  + (brow + row) * 512 + k0 + c * 8, &lA[idx * 8]);
      gload_lds16(Bw + (size_t)(bcol + row) * 512 + k0 + c * 8, &lB[idx * 8]);
    }
    __syncthreads();

    bf16x8 af[4], bfr[4];
#pragma unroll
    for (int m = 0; m < 4; ++m) {
      int row = wr * 64 + m * 16 + (lane & 15);
      af[m] = ld8(&lA[row * 32 + (lane >> 4) * 8]);
    }
#pragma unroll
    for (int n = 0; n < 4; ++n) {
      int row = wc * 64 + n * 16 + (lane & 15);
      bfr[n] = ld8(&lB[row * 32 + (lane >> 4) * 8]);
    }
#pragma unroll
    for (int m = 0; m < 4; ++m)
#pragma unroll
      for (int n = 0; n < 4; ++n)
        acc[m][n] = __builtin_amdgcn_mfma_f32_16x16x32_bf16(af[m], bfr[n], acc[m][n], 0, 0, 0);
  }

#pragma unroll
  for (int m = 0; m < 4; ++m) {
#pragma unroll
    for (int n = 0; n < 4; ++n) {
      int col = bcol + wc * 64 + n * 16 + (lane & 15);
      float bb = bias[col];
#pragma unroll
      for (int r = 0; r < 4; ++r) {
        size_t row = brow + wr * 64 + m * 16 + (lane >> 4) * 4 + r;
        float v = acc[m][n][r] + bb;
        if (XGBF16) Ch[row * 4096 + col] = f2bf(v);
        else        Cf[row * 4096 + col] = v;
      }
    }
  }
}

// ---------- phase 2: persistent recurrence (agent-scope exchange) ----------
// 32 blocks: d = bid>>4, ntile = bid&15 (128 gate-cols = 32 hidden units each).
// Race-fixed flags: each thread spins on the flag of the producer whose h-slice
// it stages. Gate repartition done in-register (4x4 lane-quad shfl transpose);
// out/fh/fc stores deferred until after the flag publish.
template <bool XGBF16>
__global__ __launch_bounds__(256, 1) void k_rnn(
    const u16* __restrict__ whp,
    const float* __restrict__ xgf, const u16* __restrict__ xgh,
    u32* __restrict__ hbuf, u32* __restrict__ flags,
    float* __restrict__ out, float* __restrict__ fh, float* __restrict__ fc) {
  const int tid  = threadIdx.x;
  const int lane = tid & 63;
  const int w    = tid >> 6;
  const int bid  = (int)blockIdx.x;
  const int d     = bid >> 4;
  const int ntile = bid & 15;

  __shared__ __align__(16) u16 hlds[32 * 512];      // 32KB, XOR-swizzled units

  // ---- Wh slice -> registers (once) ----
  const u16* wbase = whp + (size_t)(d * 2048 + ntile * 128 + w * 32) * 512;
  const int r0 = lane & 15;
  const int hi = lane >> 4;          // k-subchunk selector
  bf16x8 wf[16][2];
#pragma unroll
  for (int kk = 0; kk < 16; ++kk)
#pragma unroll
    for (int n = 0; n < 2; ++n)
      wf[kk][n] = ld8(wbase + (size_t)(n * 16 + r0) * 512 + kk * 32 + hi * 8);

  // epilogue lane mapping (per m,n): b = m*16 + hi*4 + s, j_loc = w*8 + n*4 + a
  const int aq = (lane >> 2) & 3;
  const int s  = lane & 3;
  const int swz = r0 & 7;

  float cst[2][2] = {{0.f, 0.f}, {0.f, 0.f}};

  const int FSTR = 64;                               // 256 B between flags
  u32* myflag = flags + (d * 16 + ntile) * FSTR;
  const u32* spinflag = flags + (d * 16 + ((tid & 127) >> 3)) * FSTR; // producer of my staged slice

  for (int t = 0; t < 1024; ++t) {
    const int sd = d ? (1023 - t) : t;

    // ---- xg prefetch for this thread's 4 (b,j) cells (overlaps the spin) ----
    float xgv[2][2][4];
#pragma unroll
    for (int m = 0; m < 2; ++m)
#pragma unroll
      for (int n = 0; n < 2; ++n) {
        int b  = m * 16 + hi * 4 + s;
        int jl = w * 8 + n * 4 + aq;
        size_t xo = ((size_t)(b * 1024 + sd)) * 4096 + (size_t)(d * 2048 + ntile * 128 + jl * 4);
        if (XGBF16) {
          short4v v = __builtin_nontemporal_load(reinterpret_cast<const short4v*>(xgh + xo));
          xgv[m][n][0] = bf2f((u16)v[0]); xgv[m][n][1] = bf2f((u16)v[1]);
          xgv[m][n][2] = bf2f((u16)v[2]); xgv[m][n][3] = bf2f((u16)v[3]);
        } else {
          f32x4 v = __builtin_nontemporal_load(reinterpret_cast<const f32x4*>(xgf + xo));
          xgv[m][n][0] = v[0]; xgv[m][n][1] = v[1];
          xgv[m][n][2] = v[2]; xgv[m][n][3] = v[3];
        }
      }

    // ---- wait for the producer of the h-slice this thread stages ----
    if (t > 0) {
      while (__hip_atomic_load(spinflag, __ATOMIC_RELAXED, __HIP_MEMORY_SCOPE_AGENT) < (u32)t) {}
      asm volatile("" ::: "memory");
    }

    // ---- load h (16 u64/thread, LLC-coherent) and stage swizzled ----
    const u64* hg = (const u64*)hbuf + ((size_t)(t & 1) * 2 + d) * 4096;
    u64 hv[16];
#pragma unroll
    for (int p = 0; p < 16; ++p)
      hv[p] = __hip_atomic_load(hg + p * 256 + tid, __ATOMIC_RELAXED, __HIP_MEMORY_SCOPE_AGENT);
    {
      char* hb = (char*)hlds;
#pragma unroll
      for (int p = 0; p < 16; ++p) {
        int idx = p * 256 + tid;
        int b = idx >> 7, jq = idx & 127;
        *(u64*)(hb + b * 1024 + (((jq >> 1) ^ (b & 7)) << 4) + ((jq & 1) << 3)) = hv[p];
      }
    }
    __syncthreads();

    // ---- g = h @ Wh_slice^T (MFMA) ----
    f32x4 acc[2][2] = {};
    {
      const char* hbc = (const char*)hlds;
#pragma unroll
      for (int kk = 0; kk < 16; ++kk) {
        int u0 = (((kk * 4 + hi) ^ swz) << 4);
        bf16x8 a0 = *(const bf16x8*)(hbc + r0 * 1024 + u0);
        bf16x8 a1 = *(const bf16x8*)(hbc + (16 + r0) * 1024 + u0);
#pragma unroll
        for (int n = 0; n < 2; ++n) {
          acc[0][n] = __builtin_amdgcn_mfma_f32_16x16x32_bf16(a0, wf[kk][n], acc[0][n], 0, 0, 0);
          acc[1][n] = __builtin_amdgcn_mfma_f32_16x16x32_bf16(a1, wf[kk][n], acc[1][n], 0, 0, 0);
        }
      }
    }

    // ---- in-register gate repartition (4x4 lane-quad transpose) + cell update ----
    u32* hdst = hbuf + ((size_t)((t + 1) & 1) * 2 + d) * 8192;
    float hnv[2][2], hpv[2][2];
    const bool o1 = (lane & 1) != 0;
    const bool o2 = (lane & 2) != 0;
#pragma unroll
    for (int m = 0; m < 2; ++m)
#pragma unroll
      for (int n = 0; n < 2; ++n) {
        float v0 = acc[m][n][0], v1 = acc[m][n][1], v2 = acc[m][n][2], v3 = acc[m][n][3];
        // round 1 (lane mask 1): new(l,i) for i0!=l0 <- partner's elem i^1
        float p0 = __shfl_xor(v0, 1), p1 = __shfl_xor(v1, 1);
        float p2 = __shfl_xor(v2, 1), p3 = __shfl_xor(v3, 1);
        float a0 = o1 ? p1 : v0;
        float a1 = o1 ? v1 : p0;
        float a2 = o1 ? p3 : v2;
        float a3 = o1 ? v3 : p2;
        // round 2 (lane mask 2): for i1!=l1 <- partner's elem i^2
        float q0 = __shfl_xor(a0, 2), q1 = __shfl_xor(a1, 2);
        float q2 = __shfl_xor(a2, 2), q3 = __shfl_xor(a3, 2);
        float gI = o2 ? q2 : a0;
        float gF = o2 ? q3 : a1;
        float gO = o2 ? a2 : q0;
        float gC = o2 ? a3 : q1;
        // gates: lane now owns (b = m*16+hi*4+s, j_loc = w*8+n*4+aq)
        float gi = gI + xgv[m][n][0], gf = gF + xgv[m][n][1];
        float go = gO + xgv[m][n][2], gc = gC + xgv[m][n][3];
        float cn = sigf(gf) * cst[m][n] + sigf(gi) * tanhfast(gc);
        float hn = sigf(go) * tanhfast(cn);
        cst[m][n] = cn;
        hnv[m][n] = hn;
      }

    // ---- pack h pairs (j even|odd via lane^4) and publish ----
#pragma unroll
    for (int m = 0; m < 2; ++m)
#pragma unroll
      for (int n = 0; n < 2; ++n) {
        float hp = __shfl_xor(hnv[m][n], 4);
        hpv[m][n] = hp;
        if (!(lane & 4)) {
          int b  = m * 16 + hi * 4 + s;
          int jl = w * 8 + n * 4 + aq;          // even
          u32 pk = (u32)f2bf(hnv[m][n]) | ((u32)f2bf(hp) << 16);
          __hip_atomic_store(hdst + b * 256 + ntile * 16 + (jl >> 1), pk,
                             __ATOMIC_RELAXED, __HIP_MEMORY_SCOPE_AGENT);
        }
      }

    asm volatile("s_waitcnt vmcnt(0)" ::: "memory");
    __syncthreads();
    if (tid == 0)
      __hip_atomic_store(myflag, (u32)(t + 1), __ATOMIC_RELAXED, __HIP_MEMORY_SCOPE_AGENT);

    // ---- out / final stores (off the critical path) ----
#pragma unroll
    for (int m = 0; m < 2; ++m)
#pragma unroll
      for (int n = 0; n < 2; ++n) {
        if (!(lane & 4)) {
          int b  = m * 16 + hi * 4 + s;
          int jl = w * 8 + n * 4 + aq;          // even
          int jg = ntile * 32 + jl;
          f32x2 ov; ov.x = hnv[m][n]; ov.y = hpv[m][n];
          __builtin_nontemporal_store(ov, reinterpret_cast<f32x2*>(
              out + ((size_t)(b * 1024 + sd)) * 1024 + d * 512 + jg));
        }
      }
    if (t == 1023) {
#pragma unroll
      for (int m = 0; m < 2; ++m)
#pragma unroll
        for (int n = 0; n < 2; ++n) {
          float cp = __shfl_xor(cst[m][n], 4);
          if (!(lane & 4)) {
            int b  = m * 16 + hi * 4 + s;
            int jl = w * 8 + n * 4 + aq;
            int fo = b * 1024 + d * 512 + ntile * 32 + jl;
            f32x2 hv2; hv2.x = hnv[m][n]; hv2.y = hpv[m][n];
            f32x2 cv2; cv2.x = cst[m][n]; cv2.y = cp;
            *reinterpret_cast<f32x2*>(fh + fo) = hv2;
            *reinterpret_cast<f32x2*>(fc + fo) = cv2;
          }
        }
    }
  }
}

// ---------- host ----------
extern "C" void kernel_launch(void* const* d_in, const int* in_sizes, int n_in,
                              void* d_out, int out_size, void* d_ws, size_t ws_size,
                              hipStream_t stream) {
  (void)in_sizes; (void)n_in; (void)out_size;
  const float* x    = (const float*)d_in[0];
  const float* Wx_f = (const float*)d_in[1];
  const float* Wh_f = (const float*)d_in[2];
  const float* bx_f = (const float*)d_in[3];
  const float* bh_f = (const float*)d_in[4];
  const float* Wx_b = (const float*)d_in[5];
  const float* Wh_b = (const float*)d_in[6];
  const float* bx_b = (const float*)d_in[7];
  const float* bh_b = (const float*)d_in[8];

  char* ws = (char*)d_ws;
  const size_t XG_F32 = (size_t)32768 * 4096 * 4;   // 512 MB
  const size_t XG_BF  = (size_t)32768 * 4096 * 2;   // 256 MB
  const size_t REST   = 33554432 + 4194304 + 4194304 + 16384 + 262144 + 16384;
  const bool xg_bf16 = (ws_size < XG_F32 + REST);

  size_t off = xg_bf16 ? XG_BF : XG_F32;
  float* xg_f = (float*)ws;
  u16*   xg_h = (u16*)ws;
  u16*   xh   = (u16*)(ws + off);  off += 33554432;   // x as bf16
  u16*   wall = (u16*)(ws + off);  off += 4194304;    // packed Wx (both dirs)
  u16*   whp  = (u16*)(ws + off);  off += 4194304;    // packed Wh (both dirs)
  float* bias = (float*)(ws + off); off += 16384;     // bx+bh packed
  u32*   hbuf = (u32*)(ws + off);  off += 262144;     // [2 pp][2 dir][32][256] u32
  u32*   flags = (u32*)(ws + off); off += 16384;      // 32 flags, 256 B apart

  float* out = (float*)d_out;
  float* fh  = out + (size_t)33554432;
  float* fc  = fh + 32768;

  hipError_t e = hipMemsetAsync(hbuf, 0, 262144 + 16384, stream); // h state + flags
  (void)e;
  k_conv_x<<<16384, 256, 0, stream>>>(x, xh);
  k_pack_w<<<2048, 256, 0, stream>>>(Wx_f, Wh_f, bx_f, bh_f,
                                     Wx_b, Wh_b, bx_b, bh_b, wall, whp, bias);
  if (xg_bf16) {
    k_gemm_xg<true><<<dim3(32, 256), 256, 0, stream>>>(xh, wall, bias, nullptr, xg_h);
    k_rnn<true><<<32, 256, 0, stream>>>(whp, nullptr, xg_h, hbuf, flags, out, fh, fc);
  } else {
    k_gemm_xg<false><<<dim3(32, 256), 256, 0, stream>>>(xh, wall, bias, xg_f, nullptr);
    k_rnn<false><<<32, 256, 0, stream>>>(whp, xg_f, nullptr, hbuf, flags, out, fh, fc);
  }
}

// Round 7
// 3819.904 us; speedup vs baseline: 1.4556x; 1.4556x over previous
//
#include <hip/hip_runtime.h>

typedef unsigned short u16;
typedef unsigned int u32;
typedef unsigned long long u64;
typedef __attribute__((ext_vector_type(8))) short short8v;
typedef __attribute__((ext_vector_type(8))) __bf16 bf16x8;
typedef __attribute__((ext_vector_type(4))) float f32x4;
typedef __attribute__((ext_vector_type(2))) float f32x2;

#define AS1 __attribute__((address_space(1)))
#define AS3 __attribute__((address_space(3)))

// ---------- helpers ----------
__device__ __forceinline__ u16 f2bf(float f) {
  unsigned u = __float_as_uint(f);
  u += 0x7fffu + ((u >> 16) & 1u);   // round-to-nearest-even
  return (u16)(u >> 16);
}
__device__ __forceinline__ float bf2f(u16 h) {
  return __uint_as_float(((unsigned)h) << 16);
}
__device__ __forceinline__ void gload_lds16(const void* g, void* l) {
  __builtin_amdgcn_global_load_lds((const AS1 void*)g, (AS3 void*)l, 16, 0, 0);
}
__device__ __forceinline__ bf16x8 ld8(const u16* p) {
  return __builtin_bit_cast(bf16x8, *reinterpret_cast<const short8v*>(p));
}
__device__ __forceinline__ float sigf(float x) { return 1.0f / (1.0f + __expf(-x)); }
__device__ __forceinline__ float tanhfast(float x) {
  float e = __expf(2.0f * x);
  return 1.0f - 2.0f / (e + 1.0f);
}

// ---------- setup kernels ----------
__global__ __launch_bounds__(256) void k_conv_x(const float* __restrict__ x,
                                                u16* __restrict__ xh) {
  int i = blockIdx.x * 256 + threadIdx.x;
  float4 v = reinterpret_cast<const float4*>(x)[i];
  ushort4 o;
  o.x = f2bf(v.x); o.y = f2bf(v.y); o.z = f2bf(v.z); o.w = f2bf(v.w);
  reinterpret_cast<ushort4*>(xh)[i] = o;
}

// gate-interleaved packing: n' = d*2048 + 4j + g, src row = g*512 + j
__global__ __launch_bounds__(256) void k_pack_w(
    const float* __restrict__ Wx_f, const float* __restrict__ Wh_f,
    const float* __restrict__ bx_f, const float* __restrict__ bh_f,
    const float* __restrict__ Wx_b, const float* __restrict__ Wh_b,
    const float* __restrict__ bx_b, const float* __restrict__ bh_b,
    u16* __restrict__ wall, u16* __restrict__ whp, float* __restrict__ bias) {
  int i = blockIdx.x * 256 + threadIdx.x;
  int np = i >> 7;
  int k4 = i & 127;
  int d  = np >> 11;
  int p  = np & 2047;
  int src = (p & 3) * 512 + (p >> 2);
  const float* wx = d ? Wx_b : Wx_f;
  const float* wh = d ? Wh_b : Wh_f;
  float4 vx = reinterpret_cast<const float4*>(wx + (size_t)src * 512)[k4];
  float4 vh = reinterpret_cast<const float4*>(wh + (size_t)src * 512)[k4];
  ushort4 ox, oh;
  ox.x = f2bf(vx.x); ox.y = f2bf(vx.y); ox.z = f2bf(vx.z); ox.w = f2bf(vx.w);
  oh.x = f2bf(vh.x); oh.y = f2bf(vh.y); oh.z = f2bf(vh.z); oh.w = f2bf(vh.w);
  reinterpret_cast<ushort4*>(wall + (size_t)np * 512)[k4] = ox;
  reinterpret_cast<ushort4*>(whp  + (size_t)np * 512)[k4] = oh;
  if (k4 == 0) bias[np] = d ? (bx_b[src] + bh_b[src]) : (bx_f[src] + bh_f[src]);
}

// ---------- phase 1: xg = xh @ wall^T + bias ----------
template <bool XGBF16>
__global__ __launch_bounds__(256) void k_gemm_xg(
    const u16* __restrict__ A, const u16* __restrict__ Bw,
    const float* __restrict__ bias,
    float* __restrict__ Cf, u16* __restrict__ Ch) {
  __shared__ __align__(16) u16 lA[128 * 32];
  __shared__ __align__(16) u16 lB[128 * 32];
  const int tid  = threadIdx.x;
  const int lane = tid & 63;
  const int w    = tid >> 6;
  const int wr   = w >> 1, wc = w & 1;
  const size_t brow = (size_t)blockIdx.y * 128;
  const int    bcol = blockIdx.x * 128;

  f32x4 acc[4][4] = {};

  for (int kk = 0; kk < 16; ++kk) {
    const int k0 = kk * 32;
    __syncthreads();
#pragma unroll
    for (int q = 0; q < 2; ++q) {
      int idx = q * 256 + tid;
      int row = idx >> 2, c = idx & 3;
      gload_lds16(A  + (brow + row) * 512 + k0 + c * 8, &lA[idx * 8]);
      gload_lds16(Bw + (size_t)(bcol + row) * 512 + k0 + c * 8, &lB[idx * 8]);
    }
    __syncthreads();

    bf16x8 af[4], bfr[4];
#pragma unroll
    for (int m = 0; m < 4; ++m) {
      int row = wr * 64 + m * 16 + (lane & 15);
      af[m] = ld8(&lA[row * 32 + (lane >> 4) * 8]);
    }
#pragma unroll
    for (int n = 0; n < 4; ++n) {
      int row = wc * 64 + n * 16 + (lane & 15);
      bfr[n] = ld8(&lB[row * 32 + (lane >> 4) * 8]);
    }
#pragma unroll
    for (int m = 0; m < 4; ++m)
#pragma unroll
      for (int n = 0; n < 4; ++n)
        acc[m][n] = __builtin_amdgcn_mfma_f32_16x16x32_bf16(af[m], bfr[n], acc[m][n], 0, 0, 0);
  }

#pragma unroll
  for (int m = 0; m < 4; ++m) {
#pragma unroll
    for (int n = 0; n < 4; ++n) {
      int col = bcol + wc * 64 + n * 16 + (lane & 15);
      float bb = bias[col];
#pragma unroll
      for (int r = 0; r < 4; ++r) {
        size_t row = brow + wr * 64 + m * 16 + (lane >> 4) * 4 + r;
        float v = acc[m][n][r] + bb;
        if (XGBF16) Ch[row * 4096 + col] = f2bf(v);
        else        Cf[row * 4096 + col] = v;
      }
    }
  }
}

// ---------- phase 2: persistent recurrence (agent-scope exchange) ----------
// 32 blocks: d = bid>>4, ntile = bid&15 (128 gate-cols per block).
// Round-3-proven structure. Deltas: (1) race-fixed spin (each thread waits on
// the producer of the h-slice it stages: (tid&127)>>3, constant across its 16
// chunks); (2) out/fh/fc stores AFTER the flag publish (pre-flag vmcnt drains
// only the LLC-resident h publish, not HBM writes).
template <bool XGBF16>
__global__ __launch_bounds__(256, 1) void k_rnn(
    const u16* __restrict__ whp,
    const float* __restrict__ xgf, const u16* __restrict__ xgh,
    u32* __restrict__ hbuf, u32* __restrict__ flags,
    float* __restrict__ out, float* __restrict__ fh, float* __restrict__ fc) {
  const int tid  = threadIdx.x;
  const int lane = tid & 63;
  const int w    = tid >> 6;
  const int bid  = (int)blockIdx.x;
  const int d     = bid >> 4;
  const int ntile = bid & 15;

  __shared__ __align__(16) u16 hlds[32 * 512];      // 32KB staged h (swizzled)
  __shared__ __align__(16) float gbuf[32][132];     // padded repartition buffer

  // ---- Wh slice -> registers (once) ----
  const u16* wbase = whp + (size_t)(d * 2048 + ntile * 128 + w * 32) * 512;
  bf16x8 wf[16][2];
#pragma unroll
  for (int kk = 0; kk < 16; ++kk)
#pragma unroll
    for (int n = 0; n < 2; ++n)
      wf[kk][n] = ld8(wbase + (size_t)(n * 16 + (lane & 15)) * 512 + kk * 32 + (lane >> 4) * 8);

  const int brow = tid >> 4;        // 0..15
  const int jp   = tid & 15;
  const int colbase = d * 2048 + ntile * 128 + jp * 8;
  const int r0 = lane & 15;
  const int qb = lane >> 4;
  const int swz = r0 & 7;

  float cst[2][2] = {{0.f, 0.f}, {0.f, 0.f}};

  const int FSTR = 64;                               // 256 B between flags
  u32* myflag = flags + (d * 16 + ntile) * FSTR;
  // producer of the h-slice this thread stages: u64-col = tid&127 -> slice (tid&127)>>3
  const u32* spinflag = flags + (d * 16 + ((tid & 127) >> 3)) * FSTR;

  for (int t = 0; t < 1024; ++t) {
    const int sd = d ? (1023 - t) : t;

    // ---- xg prefetch (regular cached loads; overlaps the spin) ----
    short8v xh0, xh1;
    f32x4 xf0a, xf0b, xf1a, xf1b;
    {
      size_t xoff0 = ((size_t)(brow * 1024 + sd)) * 4096 + colbase;
      size_t xoff1 = ((size_t)((16 + brow) * 1024 + sd)) * 4096 + colbase;
      if (XGBF16) {
        xh0 = *reinterpret_cast<const short8v*>(xgh + xoff0);
        xh1 = *reinterpret_cast<const short8v*>(xgh + xoff1);
      } else {
        xf0a = *reinterpret_cast<const f32x4*>(xgf + xoff0);
        xf0b = *reinterpret_cast<const f32x4*>(xgf + xoff0 + 4);
        xf1a = *reinterpret_cast<const f32x4*>(xgf + xoff1);
        xf1b = *reinterpret_cast<const f32x4*>(xgf + xoff1 + 4);
      }
    }

    // ---- wait for the producer of the h-slice this thread stages ----
    if (t > 0) {
      while (__hip_atomic_load(spinflag, __ATOMIC_RELAXED, __HIP_MEMORY_SCOPE_AGENT) < (u32)t)
        __builtin_amdgcn_s_sleep(1);
      asm volatile("" ::: "memory");
    }

    // ---- load h (16 x u64 per thread, LLC-coherent) ----
    const u64* hg = (const u64*)hbuf + ((size_t)(t & 1) * 2 + d) * 4096;
    u64 hv[16];
#pragma unroll
    for (int p = 0; p < 16; ++p)
      hv[p] = __hip_atomic_load(hg + p * 256 + tid, __ATOMIC_RELAXED, __HIP_MEMORY_SCOPE_AGENT);

    // ---- stage h to LDS: row b, 16B unit u stored at u^(b&7) ----
    {
      char* hb = (char*)hlds;
#pragma unroll
      for (int p = 0; p < 16; ++p) {
        int idx = p * 256 + tid;
        int b = idx >> 7, jq = idx & 127;
        *(u64*)(hb + b * 1024 + (((jq >> 1) ^ (b & 7)) << 4) + ((jq & 1) << 3)) = hv[p];
      }
    }
    __syncthreads();

    // ---- g = h @ Wh_slice^T (MFMA) ----
    f32x4 acc[2][2] = {};
    {
      const char* hbc = (const char*)hlds;
#pragma unroll
      for (int kk = 0; kk < 16; ++kk) {
        int u0 = (((kk * 4 + qb) ^ swz) << 4);
        bf16x8 a0 = *(const bf16x8*)(hbc + r0 * 1024 + u0);
        bf16x8 a1 = *(const bf16x8*)(hbc + (16 + r0) * 1024 + u0);
#pragma unroll
        for (int n = 0; n < 2; ++n) {
          acc[0][n] = __builtin_amdgcn_mfma_f32_16x16x32_bf16(a0, wf[kk][n], acc[0][n], 0, 0, 0);
          acc[1][n] = __builtin_amdgcn_mfma_f32_16x16x32_bf16(a1, wf[kk][n], acc[1][n], 0, 0, 0);
        }
      }
    }

    // ---- stage g to LDS for gate repartition ----
#pragma unroll
    for (int m = 0; m < 2; ++m)
#pragma unroll
      for (int n = 0; n < 2; ++n)
#pragma unroll
        for (int r = 0; r < 4; ++r)
          gbuf[m * 16 + qb * 4 + r][w * 32 + n * 16 + r0] = acc[m][n][r];
    __syncthreads();

    // ---- gates + cell update (values kept in registers) ----
    u32* hdst = hbuf + ((size_t)((t + 1) & 1) * 2 + d) * 8192;
    u32 pk[2];
    float hh[2][2];
#pragma unroll
    for (int it = 0; it < 2; ++it) {
      int b = it * 16 + brow;
      float4 g0 = *reinterpret_cast<const float4*>(&gbuf[b][jp * 8]);
      float4 g1 = *reinterpret_cast<const float4*>(&gbuf[b][jp * 8 + 4]);
      float xi0, xff0, xo0, xc0, xi1, xff1, xo1, xc1;
      if (XGBF16) {
        const short8v& xv = it ? xh1 : xh0;
        xi0 = bf2f((u16)xv[0]); xff0 = bf2f((u16)xv[1]);
        xo0 = bf2f((u16)xv[2]); xc0  = bf2f((u16)xv[3]);
        xi1 = bf2f((u16)xv[4]); xff1 = bf2f((u16)xv[5]);
        xo1 = bf2f((u16)xv[6]); xc1  = bf2f((u16)xv[7]);
      } else {
        const f32x4& va = it ? xf1a : xf0a;
        const f32x4& vb = it ? xf1b : xf0b;
        xi0 = va[0]; xff0 = va[1]; xo0 = va[2]; xc0 = va[3];
        xi1 = vb[0]; xff1 = vb[1]; xo1 = vb[2]; xc1 = vb[3];
      }
      float gi0 = g0.x + xi0, gf0 = g0.y + xff0, go0 = g0.z + xo0, gc0 = g0.w + xc0;
      float gi1 = g1.x + xi1, gf1 = g1.y + xff1, go1 = g1.z + xo1, gc1 = g1.w + xc1;
      float cn0 = sigf(gf0) * cst[it][0] + sigf(gi0) * tanhfast(gc0);
      float cn1 = sigf(gf1) * cst[it][1] + sigf(gi1) * tanhfast(gc1);
      float hn0 = sigf(go0) * tanhfast(cn0);
      float hn1 = sigf(go1) * tanhfast(cn1);
      cst[it][0] = cn0; cst[it][1] = cn1;
      pk[it] = (u32)f2bf(hn0) | ((u32)f2bf(hn1) << 16);
      hh[it][0] = hn0; hh[it][1] = hn1;
    }

    // ---- publish h, drain (only h stores outstanding matter), flag ----
#pragma unroll
    for (int it = 0; it < 2; ++it) {
      int b = it * 16 + brow;
      __hip_atomic_store(hdst + b * 256 + ntile * 16 + jp, pk[it],
                         __ATOMIC_RELAXED, __HIP_MEMORY_SCOPE_AGENT);
    }
    asm volatile("s_waitcnt vmcnt(0)" ::: "memory");
    __syncthreads();
    if (tid == 0)
      __hip_atomic_store(myflag, (u32)(t + 1), __ATOMIC_RELAXED, __HIP_MEMORY_SCOPE_AGENT);

    // ---- out / final stores (off the critical path, coalesced) ----
#pragma unroll
    for (int it = 0; it < 2; ++it) {
      int b = it * 16 + brow;
      f32x2 ov; ov.x = hh[it][0]; ov.y = hh[it][1];
      __builtin_nontemporal_store(ov, reinterpret_cast<f32x2*>(
          out + ((size_t)(b * 1024 + sd)) * 1024 + d * 512 + ntile * 32 + jp * 2));
      if (t == 1023) {
        int fo = b * 1024 + d * 512 + ntile * 32 + jp * 2;
        f32x2 hv2; hv2.x = hh[it][0]; hv2.y = hh[it][1];
        f32x2 cv2; cv2.x = cst[it][0]; cv2.y = cst[it][1];
        *reinterpret_cast<f32x2*>(fh + fo) = hv2;
        *reinterpret_cast<f32x2*>(fc + fo) = cv2;
      }
    }
  }
}

// ---------- host ----------
extern "C" void kernel_launch(void* const* d_in, const int* in_sizes, int n_in,
                              void* d_out, int out_size, void* d_ws, size_t ws_size,
                              hipStream_t stream) {
  (void)in_sizes; (void)n_in; (void)out_size;
  const float* x    = (const float*)d_in[0];
  const float* Wx_f = (const float*)d_in[1];
  const float* Wh_f = (const float*)d_in[2];
  const float* bx_f = (const float*)d_in[3];
  const float* bh_f = (const float*)d_in[4];
  const float* Wx_b = (const float*)d_in[5];
  const float* Wh_b = (const float*)d_in[6];
  const float* bx_b = (const float*)d_in[7];
  const float* bh_b = (const float*)d_in[8];

  char* ws = (char*)d_ws;
  const size_t XG_F32 = (size_t)32768 * 4096 * 4;   // 512 MB
  const size_t XG_BF  = (size_t)32768 * 4096 * 2;   // 256 MB
  const size_t REST   = 33554432 + 4194304 + 4194304 + 16384 + 262144 + 16384;
  const bool xg_bf16 = (ws_size < XG_F32 + REST);

  size_t off = xg_bf16 ? XG_BF : XG_F32;
  float* xg_f = (float*)ws;
  u16*   xg_h = (u16*)ws;
  u16*   xh   = (u16*)(ws + off);  off += 33554432;   // x as bf16
  u16*   wall = (u16*)(ws + off);  off += 4194304;    // packed Wx (both dirs)
  u16*   whp  = (u16*)(ws + off);  off += 4194304;    // packed Wh (both dirs)
  float* bias = (float*)(ws + off); off += 16384;     // bx+bh packed
  u32*   hbuf = (u32*)(ws + off);  off += 262144;     // [2 pp][2 dir][32][256] u32
  u32*   flags = (u32*)(ws + off); off += 16384;      // 32 flags, 256 B apart

  float* out = (float*)d_out;
  float* fh  = out + (size_t)33554432;
  float* fc  = fh + 32768;

  hipError_t e = hipMemsetAsync(hbuf, 0, 262144 + 16384, stream); // h state + flags
  (void)e;
  k_conv_x<<<16384, 256, 0, stream>>>(x, xh);
  k_pack_w<<<2048, 256, 0, stream>>>(Wx_f, Wh_f, bx_f, bh_f,
                                     Wx_b, Wh_b, bx_b, bh_b, wall, whp, bias);
  if (xg_bf16) {
    k_gemm_xg<true><<<dim3(32, 256), 256, 0, stream>>>(xh, wall, bias, nullptr, xg_h);
    k_rnn<true><<<32, 256, 0, stream>>>(whp, nullptr, xg_h, hbuf, flags, out, fh, fc);
  } else {
    k_gemm_xg<false><<<dim3(32, 256), 256, 0, stream>>>(xh, wall, bias, xg_f, nullptr);
    k_rnn<false><<<32, 256, 0, stream>>>(whp, xg_f, nullptr, hbuf, flags, out, fh, fc);
  }
}